// Round 5
// baseline (349.992 us; speedup 1.0000x reference)
//
#include <hip/hip_runtime.h>

// Decoder layer: x + attn(LN1(x)); then + FFN(LN2(.))
// B=2, S=2048, D=1024, H=16, DK=64, FF=4096. fp32 in/out; f16 MFMA inside.

#define S_LEN 2048
#define DMODEL 1024
#define NHEADS 16
#define FFDIM 4096
#define MROWS 4096   // B*S

typedef _Float16 f16;
typedef _Float16 f16x8 __attribute__((ext_vector_type(8)));
typedef float f32x4 __attribute__((ext_vector_type(4)));
typedef unsigned long long u64;
typedef unsigned long long u64x2 __attribute__((ext_vector_type(2)));

union Frag { f16x8 h; u64 q[2]; };

__device__ __forceinline__ f32x4 mfma16(f16x8 a, f16x8 b, f32x4 c) {
  return __builtin_amdgcn_mfma_f32_16x16x32_f16(a, b, c, 0, 0, 0);
}

typedef __attribute__((address_space(1))) const void gvoid;
typedef __attribute__((address_space(3))) void lvoid;

__device__ __forceinline__ void gload16(const f16* gp, f16* lp) {
  __builtin_amdgcn_global_load_lds((gvoid*)gp, (lvoid*)lp, 16, 0, 0);
}

// ---------------- weight transpose+convert: W[K][N] fp32 -> Wt[N][K] f16 ----
__global__ __launch_bounds__(256) void wtrans_kernel(const float* __restrict__ W,
                                                     f16* __restrict__ Wt,
                                                     int K, int N) {
  __shared__ f16 tile[32][33];
  const int n0 = blockIdx.x * 32, k0 = blockIdx.y * 32;
  const int tx = threadIdx.x & 31, ty = threadIdx.x >> 5;  // 32 x 8
  for (int i = 0; i < 4; i++) {
    int k = ty + i * 8;
    tile[k][tx] = (f16)W[(size_t)(k0 + k) * N + n0 + tx];
  }
  __syncthreads();
  for (int i = 0; i < 4; i++) {
    int n = ty + i * 8;
    Wt[(size_t)(n0 + n) * K + k0 + tx] = tile[tx][n];
  }
}

__global__ void bias_concat_kernel(const float* __restrict__ bq,
                                   const float* __restrict__ bk,
                                   const float* __restrict__ bv,
                                   float* __restrict__ out) {
  int i = blockIdx.x * 256 + threadIdx.x;  // 3072 total
  float v = (i < 1024) ? bq[i] : (i < 2048) ? bk[i - 1024] : bv[i - 2048];
  out[i] = v;
}

// ---------------- LayerNorm fp32 -> f16 ------------------------------------
__global__ __launch_bounds__(256) void ln_kernel(const float* __restrict__ x,
                                                 const float* __restrict__ gw,
                                                 const float* __restrict__ bw,
                                                 f16* __restrict__ out) {
  const int row = blockIdx.x, t = threadIdx.x;
  const float* xr = x + (size_t)row * DMODEL;
  float4 v = *(const float4*)(xr + t * 4);
  float s = v.x + v.y + v.z + v.w;
  float s2 = v.x * v.x + v.y * v.y + v.z * v.z + v.w * v.w;
  for (int off = 1; off < 64; off <<= 1) {
    s += __shfl_xor(s, off);
    s2 += __shfl_xor(s2, off);
  }
  __shared__ float red[8];
  const int w = t >> 6, lane = t & 63;
  if (lane == 0) { red[w] = s; red[w + 4] = s2; }
  __syncthreads();
  s = red[0] + red[1] + red[2] + red[3];
  s2 = red[4] + red[5] + red[6] + red[7];
  float mu = s * (1.0f / DMODEL);
  float var = s2 * (1.0f / DMODEL) - mu * mu;
  float rstd = rsqrtf(var + 1e-6f);
  float4 g4 = *(const float4*)(gw + t * 4);
  float4 b4 = *(const float4*)(bw + t * 4);
  union { f16 h[4]; u64 q; } o;
  o.h[0] = (f16)((v.x - mu) * rstd * g4.x + b4.x);
  o.h[1] = (f16)((v.y - mu) * rstd * g4.y + b4.y);
  o.h[2] = (f16)((v.z - mu) * rstd * g4.z + b4.z);
  o.h[3] = (f16)((v.w - mu) * rstd * g4.w + b4.w);
  *(u64*)(out + (size_t)row * DMODEL + t * 4) = o.q;
}

// ---------------- GEMM: C = A[M][K] @ Bt[N][K]^T + bias ---------------------
// BK=64, global_load_lds width-16 staging, DOUBLE-BUFFERED LDS: stage(t+1)
// issued before compute(t), single barrier per K-step (T3 minimum recipe).
// Both-sides XOR swizzle (rule #21): global source 16B-block index XOR'd with
// (row&7); LDS dest linear; fragment reads use the same XOR -> net-linear
// K-mapping, identical for A and B => exact.
template <int BM, int BN>
__global__ __launch_bounds__(256, 2) void gemm2(const f16* __restrict__ A, int lda,
                                                const f16* __restrict__ Bt, int ldb,
                                                const float* __restrict__ bias,
                                                const float* __restrict__ res,
                                                float* __restrict__ outf,
                                                f16* __restrict__ outh, int ldo,
                                                int N, int K, int relu) {
  constexpr int MT = BM / 32, NT = BN / 32;
  __shared__ f16 As[2][BM * 64];
  __shared__ f16 Bs[2][BN * 64];
  const int m0 = blockIdx.y * BM, n0 = blockIdx.x * BN;
  const int t = threadIdx.x;
  const int lane = t & 63, w = t >> 6;
  const int wr = w >> 1, wc = w & 1;
  const int rA = lane & 15, g = lane >> 4;

  f32x4 acc[MT][NT] = {};

  auto stage = [&](int k0, int buf) {
#pragma unroll
    for (int p = 0; p < BM / 32; p++) {
      const int chunk = p * 256 + w * 64 + lane;
      const int row = chunk >> 3;
      const int cbg = ((chunk & 7) ^ (row & 7)) * 8;  // pre-swizzled source col
      gload16(A + (size_t)(m0 + row) * lda + k0 + cbg,
              &As[buf][(p * 256 + w * 64) * 8]);
    }
#pragma unroll
    for (int p = 0; p < BN / 32; p++) {
      const int chunk = p * 256 + w * 64 + lane;
      const int row = chunk >> 3;
      const int cbg = ((chunk & 7) ^ (row & 7)) * 8;
      gload16(Bt + (size_t)(n0 + row) * ldb + k0 + cbg,
              &Bs[buf][(p * 256 + w * 64) * 8]);
    }
  };

  stage(0, 0);
  int cur = 0;
  for (int k0 = 0; k0 < K; k0 += 64) {
    __syncthreads();  // stage(k0) complete; all reads of buf cur^1 done
    if (k0 + 64 < K) stage(k0 + 64, cur ^ 1);  // overlaps compute below

#pragma unroll
    for (int ks = 0; ks < 2; ks++) {
      Frag a[MT], b[NT];
#pragma unroll
      for (int mt = 0; mt < MT; mt++) {
        const int row = wr * (BM / 2) + mt * 16 + rA;
        a[mt].h = *(const f16x8*)(&As[cur][row * 64 + ((ks * 4 + g) ^ (row & 7)) * 8]);
      }
#pragma unroll
      for (int nt = 0; nt < NT; nt++) {
        const int row = wc * (BN / 2) + nt * 16 + rA;
        b[nt].h = *(const f16x8*)(&Bs[cur][row * 64 + ((ks * 4 + g) ^ (row & 7)) * 8]);
      }
#pragma unroll
      for (int mt = 0; mt < MT; mt++)
#pragma unroll
        for (int nt = 0; nt < NT; nt++)
          acc[mt][nt] = mfma16(a[mt].h, b[nt].h, acc[mt][nt]);
    }
    cur ^= 1;
  }

#pragma unroll
  for (int mt = 0; mt < MT; mt++) {
#pragma unroll
    for (int nt = 0; nt < NT; nt++) {
      const int col = n0 + wc * (BN / 2) + nt * 16 + rA;
      const int rowb = m0 + wr * (BM / 2) + mt * 16 + g * 4;
      const float bs = bias[col];
#pragma unroll
      for (int r = 0; r < 4; r++) {
        float v = acc[mt][nt][r] + bs;
        if (relu) v = fmaxf(v, 0.0f);
        if (res) v += res[(size_t)(rowb + r) * N + col];
        if (outf) outf[(size_t)(rowb + r) * N + col] = v;
        if (outh) outh[(size_t)(rowb + r) * ldo + col] = (f16)v;
      }
    }
  }
}

// ---------------- V transpose: qkv v-cols -> vt[bh*64+dk][s] ----------------
__global__ __launch_bounds__(256) void vtrans_kernel(const f16* __restrict__ qkv,
                                                     f16* __restrict__ vt) {
  const int bh = blockIdx.y;                 // 0..31
  const int s0 = blockIdx.x * 64;
  const int b = bh >> 4, h = bh & 15;
  __shared__ f16 tile[64][72];               // [s][dk]
  const int t = threadIdx.x;
  for (int pass = 0; pass < 2; pass++) {
    int sl = (t >> 3) + pass * 32;
    int dk0 = (t & 7) * 8;
    u64x2 v = *(const u64x2*)(qkv + (size_t)(b * S_LEN + s0 + sl) * 3072 + 2048 + h * 64 + dk0);
    *(u64x2*)(&tile[sl][dk0]) = v;
  }
  __syncthreads();
  for (int pass = 0; pass < 2; pass++) {
    int dk = (t >> 3) + pass * 32;
    int sc = (t & 7) * 8;
    union { u64x2 q; f16 u[8]; } o;
    for (int j = 0; j < 8; j++) o.u[j] = tile[sc + j][dk];
    *(u64x2*)(vt + (size_t)(bh * 64 + dk) * S_LEN + s0 + sc) = o.q;
  }
}

// ---------------- flash attention: 4 waves x 16 q-rows, qtile 64 ------------
// Occupancy: LDS = 16K(Ks)+16K(Vs)+9.2K(Ps) = 41.2K -> 3 blocks/CU (12 waves).
// Q pre-scaled by 0.125*log2(e): softmax runs natively in exp2 domain.
// Defer-max (T13, THR=8): skip o/l rescale when no row max grew by >8.
__global__ __launch_bounds__(256, 3) void attn_kernel(const f16* __restrict__ qkv,
                                                      const f16* __restrict__ vt,
                                                      f16* __restrict__ attn_out) {
  const int qt0 = blockIdx.x * 64;    // q-tile base
  const int bh = blockIdx.y;          // 0..31
  const int b = bh >> 4, h = bh & 15;
  const int t = threadIdx.x;
  const int lane = t & 63, w = t >> 6;
  const int rA = lane & 15, g = lane >> 4;

  __shared__ f16 Ks[2][64 * 64];      // [kv 64][dk 64], swizzled 16B blocks
  __shared__ f16 Vs[2][64 * 64];      // [dk 64][kv 64], swizzled 16B blocks
  __shared__ f16 Ps[4][16 * 72];      // per-wave P: [q 16][kv 64 + pad 8]

  // Q fragment rows: qt0 + w*16 + rA; pre-scale by 0.125*log2e
  Frag qf[2];
#pragma unroll
  for (int kt = 0; kt < 2; kt++) {
    const f16* p = qkv + (size_t)(b * S_LEN + qt0 + w * 16 + rA) * 3072 +
                   h * 64 + kt * 32 + 8 * g;
    f16x8 v = *(const f16x8*)p;
#pragma unroll
    for (int j = 0; j < 8; j++) v[j] = v[j] * (f16)0.18033688f;
    qf[kt].h = v;
  }

  float mR[4], lR[4];
  f32x4 o[4] = {};
#pragma unroll
  for (int r = 0; r < 4; r++) { mR[r] = -3.0e38f; lR[r] = 0.0f; }

  f16* Pw = &Ps[w][0];

#define STAGE_KV(kv0_, buf_)                                                     \
  {                                                                              \
    _Pragma("unroll") for (int i = 0; i < 2; i++) {                              \
      int C = i * 256 + w * 64 + lane;                                           \
      int row = C >> 3;                                                          \
      int cbg = ((C & 7) ^ (row & 7)) * 8;                                       \
      gload16(qkv + (size_t)(b * S_LEN + (kv0_) + row) * 3072 + 1024 + h * 64 + cbg, \
              &Ks[buf_][(i * 256 + w * 64) * 8]);                                \
      gload16(vt + (size_t)(bh * 64 + row) * S_LEN + (kv0_) + cbg,               \
              &Vs[buf_][(i * 256 + w * 64) * 8]);                                \
    }                                                                            \
  }

  int cur = 0;
  STAGE_KV(0, 0);

  for (int kv0 = 0; kv0 < S_LEN; kv0 += 64) {
    __syncthreads();  // buf[cur] staged; prev reads done
    if (kv0 + 64 < S_LEN) STAGE_KV(kv0 + 64, cur ^ 1);  // overlaps compute

    // ---- QK^T (in exp2 domain)
    Frag kf[4][2];
#pragma unroll
    for (int nt = 0; nt < 4; nt++)
#pragma unroll
      for (int kt = 0; kt < 2; kt++) {
        int row = nt * 16 + rA;
        int cbl = (kt * 4 + g) ^ (row & 7);
        kf[nt][kt].h = *(const f16x8*)(&Ks[cur][row * 64 + cbl * 8]);
      }
    f32x4 s[4] = {};
#pragma unroll
    for (int nt = 0; nt < 4; nt++)
#pragma unroll
      for (int kt = 0; kt < 2; kt++)
        s[nt] = mfma16(qf[kt].h, kf[nt][kt].h, s[nt]);

    // ---- online softmax (C layout: row q = g*4 + r, col kv = nt*16 + rA)
    float mx[4];
    bool ok = true;
#pragma unroll
    for (int r = 0; r < 4; r++) {
      float m0 = fmaxf(fmaxf(s[0][r], s[1][r]), fmaxf(s[2][r], s[3][r]));
      m0 = fmaxf(m0, __shfl_xor(m0, 1));
      m0 = fmaxf(m0, __shfl_xor(m0, 2));
      m0 = fmaxf(m0, __shfl_xor(m0, 4));
      m0 = fmaxf(m0, __shfl_xor(m0, 8));
      mx[r] = m0;
      ok = ok && (m0 - mR[r] <= 8.0f);
    }
    if (!__all(ok)) {  // rescale path (rare after first tiles)
#pragma unroll
      for (int r = 0; r < 4; r++) {
        float mn = fmaxf(mR[r], mx[r]);
        float alpha = exp2f(mR[r] - mn);
        mR[r] = mn;
        lR[r] *= alpha;
#pragma unroll
        for (int d = 0; d < 4; d++) o[d][r] *= alpha;
      }
    }
#pragma unroll
    for (int r = 0; r < 4; r++) {
      float rs = 0.0f;
#pragma unroll
      for (int nt = 0; nt < 4; nt++) {
        float e0 = exp2f(s[nt][r] - mR[r]);
        s[nt][r] = e0;
        rs += e0;
      }
      rs += __shfl_xor(rs, 1);
      rs += __shfl_xor(rs, 2);
      rs += __shfl_xor(rs, 4);
      rs += __shfl_xor(rs, 8);
      lR[r] += rs;
    }

    // ---- P -> per-wave LDS (wave-local; no block barrier needed)
#pragma unroll
    for (int nt = 0; nt < 4; nt++)
#pragma unroll
      for (int r = 0; r < 4; r++)
        Pw[(g * 4 + r) * 72 + nt * 16 + rA] = (f16)s[nt][r];

    // ---- PV: o[d] += P @ V^T
    Frag vf[4][2];
#pragma unroll
    for (int d = 0; d < 4; d++)
#pragma unroll
      for (int ks = 0; ks < 2; ks++) {
        int row = d * 16 + rA;
        int cbl = (ks * 4 + g) ^ (row & 7);
        vf[d][ks].h = *(const f16x8*)(&Vs[cur][row * 64 + cbl * 8]);
      }
    Frag pf[2];
#pragma unroll
    for (int ks = 0; ks < 2; ks++)
      pf[ks].h = *(const f16x8*)(Pw + rA * 72 + ks * 32 + 8 * g);
#pragma unroll
    for (int d = 0; d < 4; d++)
#pragma unroll
      for (int ks = 0; ks < 2; ks++)
        o[d] = mfma16(pf[ks].h, vf[d][ks].h, o[d]);

    cur ^= 1;
  }

  // ---- normalize + store (C layout)
  float inv[4];
#pragma unroll
  for (int r = 0; r < 4; r++) inv[r] = 1.0f / lR[r];
#pragma unroll
  for (int d = 0; d < 4; d++)
#pragma unroll
    for (int r = 0; r < 4; r++) {
      int row = qt0 + w * 16 + g * 4 + r;
      attn_out[(size_t)(b * S_LEN + row) * DMODEL + h * 64 + d * 16 + rA] =
          (f16)(o[d][r] * inv[r]);
    }
#undef STAGE_KV
}

// ---------------------------------------------------------------------------
extern "C" void kernel_launch(void* const* d_in, const int* in_sizes, int n_in,
                              void* d_out, int out_size, void* d_ws, size_t ws_size,
                              hipStream_t stream) {
  const float* x     = (const float*)d_in[0];
  const float* Wq    = (const float*)d_in[1];
  const float* bq    = (const float*)d_in[2];
  const float* Wk    = (const float*)d_in[3];
  const float* bk    = (const float*)d_in[4];
  const float* Wv    = (const float*)d_in[5];
  const float* bv    = (const float*)d_in[6];
  const float* Wo    = (const float*)d_in[7];
  const float* bo    = (const float*)d_in[8];
  const float* W1    = (const float*)d_in[9];
  const float* b1    = (const float*)d_in[10];
  const float* W2    = (const float*)d_in[11];
  const float* b2    = (const float*)d_in[12];
  const float* ln1g  = (const float*)d_in[13];
  const float* ln1b  = (const float*)d_in[14];
  const float* ln2g  = (const float*)d_in[15];
  const float* ln2b  = (const float*)d_in[16];
  float* out = (float*)d_out;
  char* ws = (char*)d_ws;

  size_t off = 0;
  f16* wqkv_t = (f16*)(ws + off); off += (size_t)3072 * 1024 * 2;   // 6 MB
  f16* wo_t   = (f16*)(ws + off); off += (size_t)1024 * 1024 * 2;   // 2 MB
  f16* w1_t   = (f16*)(ws + off); off += (size_t)4096 * 1024 * 2;   // 8 MB
  f16* w2_t   = (f16*)(ws + off); off += (size_t)1024 * 4096 * 2;   // 8 MB
  float* bqkv = (float*)(ws + off); off += 3072 * 4;                // 12 KB
  f16* regB   = (f16*)(ws + off); off += (size_t)MROWS * 1024 * 2;  // 8 MB (xln/attn_out/xln2)
  f16* qkv    = (f16*)(ws + off); off += (size_t)MROWS * 3072 * 2;  // 24 MB
  f16* vt     = (f16*)(ws + off); off += (size_t)MROWS * 1024 * 2;  // 8 MB
  f16* hbuf   = qkv;  // overlay: qkv+vt (32MB) dead after attention; FFN h = 32MB

  // 1. weights -> f16 transposed
  wtrans_kernel<<<dim3(32, 32), 256, 0, stream>>>(Wq, wqkv_t, 1024, 1024);
  wtrans_kernel<<<dim3(32, 32), 256, 0, stream>>>(Wk, wqkv_t + (size_t)1024 * 1024, 1024, 1024);
  wtrans_kernel<<<dim3(32, 32), 256, 0, stream>>>(Wv, wqkv_t + (size_t)2048 * 1024, 1024, 1024);
  wtrans_kernel<<<dim3(32, 32), 256, 0, stream>>>(Wo, wo_t, 1024, 1024);
  wtrans_kernel<<<dim3(128, 32), 256, 0, stream>>>(W1, w1_t, 1024, 4096);
  wtrans_kernel<<<dim3(32, 128), 256, 0, stream>>>(W2, w2_t, 4096, 1024);
  bias_concat_kernel<<<12, 256, 0, stream>>>(bq, bk, bv, bqkv);

  // 2. LN1(x) -> regB (f16)
  ln_kernel<<<MROWS, 256, 0, stream>>>(x, ln1g, ln1b, regB);

  // 3. fused QKV projection: [4096,1024] @ [1024,3072]
  gemm2<128, 128><<<dim3(24, 32), 256, 0, stream>>>(regB, 1024, wqkv_t, 1024, bqkv,
                                                    nullptr, nullptr, qkv, 3072,
                                                    3072, 1024, 0);
  // 4. V -> [bh*64+dk][s]
  vtrans_kernel<<<dim3(32, 32), 256, 0, stream>>>(qkv, vt);

  // 5. attention -> regB (f16), 4 waves x 16 q-rows, 1024 blocks
  attn_kernel<<<dim3(32, 32), 256, 0, stream>>>(qkv, vt, regB);

  // 6. O projection + residual x -> d_out (fp32); 128x64 tiles -> 512 blocks
  gemm2<128, 64><<<dim3(16, 32), 256, 0, stream>>>(regB, 1024, wo_t, 1024, bo,
                                                   x, out, nullptr, 0,
                                                   1024, 1024, 0);
  // 7. LN2(d_out) -> regB
  ln_kernel<<<MROWS, 256, 0, stream>>>(out, ln2g, ln2b, regB);

  // 8. FFN1 + ReLU: [4096,1024]@[1024,4096] -> hbuf (f16)
  gemm2<128, 128><<<dim3(32, 32), 256, 0, stream>>>(regB, 1024, w1_t, 1024, b1,
                                                    nullptr, nullptr, hbuf, 4096,
                                                    4096, 1024, 1);
  // 9. FFN2 + residual: [4096,4096]@[4096,1024] + d_out -> d_out; 512 blocks
  gemm2<128, 64><<<dim3(16, 32), 256, 0, stream>>>(hbuf, 4096, w2_t, 4096, b2,
                                                   out, out, nullptr, 0,
                                                   1024, 4096, 0);
}

// Round 6
// 298.385 us; speedup vs baseline: 1.1730x; 1.1730x over previous
//
#include <hip/hip_runtime.h>

// Decoder layer: x + attn(LN1(x)); then + FFN(LN2(.))
// B=2, S=2048, D=1024, H=16, DK=64, FF=4096. fp32 in/out; f16 MFMA inside.

#define S_LEN 2048
#define DMODEL 1024
#define NHEADS 16
#define FFDIM 4096
#define MROWS 4096   // B*S

typedef _Float16 f16;
typedef _Float16 f16x8 __attribute__((ext_vector_type(8)));
typedef float f32x4 __attribute__((ext_vector_type(4)));
typedef unsigned long long u64;
typedef unsigned long long u64x2 __attribute__((ext_vector_type(2)));

union Frag { f16x8 h; u64 q[2]; f16 e[8]; };

__device__ __forceinline__ f32x4 mfma16(f16x8 a, f16x8 b, f32x4 c) {
  return __builtin_amdgcn_mfma_f32_16x16x32_f16(a, b, c, 0, 0, 0);
}

typedef __attribute__((address_space(1))) const void gvoid;
typedef __attribute__((address_space(3))) void lvoid;

__device__ __forceinline__ void gload16(const f16* gp, f16* lp) {
  __builtin_amdgcn_global_load_lds((gvoid*)gp, (lvoid*)lp, 16, 0, 0);
}

// ---------------- weight transpose+convert: W[K][N] fp32 -> Wt[N][K] f16 ----
__global__ __launch_bounds__(256) void wtrans_kernel(const float* __restrict__ W,
                                                     f16* __restrict__ Wt,
                                                     int K, int N) {
  __shared__ f16 tile[32][33];
  const int n0 = blockIdx.x * 32, k0 = blockIdx.y * 32;
  const int tx = threadIdx.x & 31, ty = threadIdx.x >> 5;  // 32 x 8
  for (int i = 0; i < 4; i++) {
    int k = ty + i * 8;
    tile[k][tx] = (f16)W[(size_t)(k0 + k) * N + n0 + tx];
  }
  __syncthreads();
  for (int i = 0; i < 4; i++) {
    int n = ty + i * 8;
    Wt[(size_t)(n0 + n) * K + k0 + tx] = tile[tx][n];
  }
}

__global__ void bias_concat_kernel(const float* __restrict__ bq,
                                   const float* __restrict__ bk,
                                   const float* __restrict__ bv,
                                   float* __restrict__ out) {
  int i = blockIdx.x * 256 + threadIdx.x;  // 3072 total
  float v = (i < 1024) ? bq[i] : (i < 2048) ? bk[i - 1024] : bv[i - 2048];
  out[i] = v;
}

// ---------------- LayerNorm fp32 -> f16 ------------------------------------
__global__ __launch_bounds__(256) void ln_kernel(const float* __restrict__ x,
                                                 const float* __restrict__ gw,
                                                 const float* __restrict__ bw,
                                                 f16* __restrict__ out) {
  const int row = blockIdx.x, t = threadIdx.x;
  const float* xr = x + (size_t)row * DMODEL;
  float4 v = *(const float4*)(xr + t * 4);
  float s = v.x + v.y + v.z + v.w;
  float s2 = v.x * v.x + v.y * v.y + v.z * v.z + v.w * v.w;
  for (int off = 1; off < 64; off <<= 1) {
    s += __shfl_xor(s, off);
    s2 += __shfl_xor(s2, off);
  }
  __shared__ float red[8];
  const int w = t >> 6, lane = t & 63;
  if (lane == 0) { red[w] = s; red[w + 4] = s2; }
  __syncthreads();
  s = red[0] + red[1] + red[2] + red[3];
  s2 = red[4] + red[5] + red[6] + red[7];
  float mu = s * (1.0f / DMODEL);
  float var = s2 * (1.0f / DMODEL) - mu * mu;
  float rstd = rsqrtf(var + 1e-6f);
  float4 g4 = *(const float4*)(gw + t * 4);
  float4 b4 = *(const float4*)(bw + t * 4);
  union { f16 h[4]; u64 q; } o;
  o.h[0] = (f16)((v.x - mu) * rstd * g4.x + b4.x);
  o.h[1] = (f16)((v.y - mu) * rstd * g4.y + b4.y);
  o.h[2] = (f16)((v.z - mu) * rstd * g4.z + b4.z);
  o.h[3] = (f16)((v.w - mu) * rstd * g4.w + b4.w);
  *(u64*)(out + (size_t)row * DMODEL + t * 4) = o.q;
}

// ---------------- GEMM: C = A[M][K] @ Bt[N][K]^T + bias ---------------------
// BK=64, global_load_lds width-16 staging, double-buffered LDS, one barrier
// per K-step. Both-sides XOR swizzle (rule #21). Consistent A/B K-mapping.
template <int BM, int BN>
__global__ __launch_bounds__(256, 2) void gemm2(const f16* __restrict__ A, int lda,
                                                const f16* __restrict__ Bt, int ldb,
                                                const float* __restrict__ bias,
                                                const float* __restrict__ res,
                                                float* __restrict__ outf,
                                                f16* __restrict__ outh, int ldo,
                                                int N, int K, int relu) {
  constexpr int MT = BM / 32, NT = BN / 32;
  __shared__ f16 As[2][BM * 64];
  __shared__ f16 Bs[2][BN * 64];
  const int m0 = blockIdx.y * BM, n0 = blockIdx.x * BN;
  const int t = threadIdx.x;
  const int lane = t & 63, w = t >> 6;
  const int wr = w >> 1, wc = w & 1;
  const int rA = lane & 15, g = lane >> 4;

  f32x4 acc[MT][NT] = {};

  auto stage = [&](int k0, int buf) {
#pragma unroll
    for (int p = 0; p < BM / 32; p++) {
      const int chunk = p * 256 + w * 64 + lane;
      const int row = chunk >> 3;
      const int cbg = ((chunk & 7) ^ (row & 7)) * 8;  // pre-swizzled source col
      gload16(A + (size_t)(m0 + row) * lda + k0 + cbg,
              &As[buf][(p * 256 + w * 64) * 8]);
    }
#pragma unroll
    for (int p = 0; p < BN / 32; p++) {
      const int chunk = p * 256 + w * 64 + lane;
      const int row = chunk >> 3;
      const int cbg = ((chunk & 7) ^ (row & 7)) * 8;
      gload16(Bt + (size_t)(n0 + row) * ldb + k0 + cbg,
              &Bs[buf][(p * 256 + w * 64) * 8]);
    }
  };

  stage(0, 0);
  int cur = 0;
  for (int k0 = 0; k0 < K; k0 += 64) {
    __syncthreads();  // stage(k0) complete; all reads of buf cur^1 done
    if (k0 + 64 < K) stage(k0 + 64, cur ^ 1);  // overlaps compute below

#pragma unroll
    for (int ks = 0; ks < 2; ks++) {
      Frag a[MT], b[NT];
#pragma unroll
      for (int mt = 0; mt < MT; mt++) {
        const int row = wr * (BM / 2) + mt * 16 + rA;
        a[mt].h = *(const f16x8*)(&As[cur][row * 64 + ((ks * 4 + g) ^ (row & 7)) * 8]);
      }
#pragma unroll
      for (int nt = 0; nt < NT; nt++) {
        const int row = wc * (BN / 2) + nt * 16 + rA;
        b[nt].h = *(const f16x8*)(&Bs[cur][row * 64 + ((ks * 4 + g) ^ (row & 7)) * 8]);
      }
#pragma unroll
      for (int mt = 0; mt < MT; mt++)
#pragma unroll
        for (int nt = 0; nt < NT; nt++)
          acc[mt][nt] = mfma16(a[mt].h, b[nt].h, acc[mt][nt]);
    }
    cur ^= 1;
  }

#pragma unroll
  for (int mt = 0; mt < MT; mt++) {
#pragma unroll
    for (int nt = 0; nt < NT; nt++) {
      const int col = n0 + wc * (BN / 2) + nt * 16 + rA;
      const int rowb = m0 + wr * (BM / 2) + mt * 16 + g * 4;
      const float bs = bias[col];
#pragma unroll
      for (int r = 0; r < 4; r++) {
        float v = acc[mt][nt][r] + bs;
        if (relu) v = fmaxf(v, 0.0f);
        if (res) v += res[(size_t)(rowb + r) * N + col];
        if (outf) outf[(size_t)(rowb + r) * N + col] = v;
        if (outh) outh[(size_t)(rowb + r) * ldo + col] = (f16)v;
      }
    }
  }
}

// ---------------- V transpose: qkv v-cols -> vt[bh*64+dk][s], k-slot perm ---
// Within each 64-aligned S-chunk, position pos holds kv index
// kv(pos) = (pos&32) | ((pos&4)<<2) | ((pos&0x18)>>1) | (pos&3)
// so a 16B read at pos = j*32+8g gives kv {j*32+4g+i, j*32+16+4g+i} — the
// PV A-fragment content matching the QK^T C-row -> PV B-slot alignment.
__global__ __launch_bounds__(256) void vtrans_kernel(const f16* __restrict__ qkv,
                                                     f16* __restrict__ vt) {
  const int bh = blockIdx.y;                 // 0..31
  const int s0 = blockIdx.x * 64;
  const int b = bh >> 4, h = bh & 15;
  __shared__ f16 tile[64][72];               // [s][dk]
  const int t = threadIdx.x;
  for (int pass = 0; pass < 2; pass++) {
    int sl = (t >> 3) + pass * 32;
    int dk0 = (t & 7) * 8;
    u64x2 v = *(const u64x2*)(qkv + (size_t)(b * S_LEN + s0 + sl) * 3072 + 2048 + h * 64 + dk0);
    *(u64x2*)(&tile[sl][dk0]) = v;
  }
  __syncthreads();
  for (int pass = 0; pass < 2; pass++) {
    int dk = (t >> 3) + pass * 32;
    int sc = (t & 7) * 8;
    union { u64x2 q; f16 u[8]; } o;
    for (int j = 0; j < 8; j++) {
      int pos = sc + j;
      int kv = (pos & 32) | ((pos & 4) << 2) | ((pos & 0x18) >> 1) | (pos & 3);
      o.u[j] = tile[kv][dk];
    }
    *(u64x2*)(vt + (size_t)(bh * 64 + dk) * S_LEN + s0 + sc) = o.q;
  }
}

// ---------------- flash attention: swapped QK^T, zero-shuffle PV ------------
// 4 waves x 16 q-rows (q = qw0 + rA, one q per lane). s = mfma(K, Q):
// C layout (m89): col = q = rA, row = kv = nt*16 + g*4 + reg. Softmax is
// lane-local (15 in-lane ops + 2 shfls). exp2'd scores convert f16 in-lane
// and feed PV's B-operand directly (C-row <-> B-k-slot alignment; V's
// A-fragment uses the same slot convention via the permuted vt).
__global__ __launch_bounds__(256, 4) void attn_kernel(const f16* __restrict__ qkv,
                                                      const f16* __restrict__ vt,
                                                      f16* __restrict__ attn_out) {
  const int qt0 = blockIdx.x * 64;    // q-tile base (64 rows/block)
  const int bh = blockIdx.y;          // 0..31
  const int b = bh >> 4, h = bh & 15;
  const int t = threadIdx.x;
  const int lane = t & 63, w = t >> 6;
  const int rA = lane & 15, g = lane >> 4;

  __shared__ f16 Ks[2][64 * 64];      // [kv 64][dk 64], swizzled 16B blocks
  __shared__ f16 Vs[2][64 * 64];      // [dk 64][kv-perm 64], swizzled blocks

  // Q fragment (B-operand): col q = qt0 + w*16 + rA; pre-scale 0.125*log2e
  const int qrow = qt0 + w * 16 + rA;
  Frag qf[2];
#pragma unroll
  for (int kt = 0; kt < 2; kt++) {
    const f16* p = qkv + (size_t)(b * S_LEN + qrow) * 3072 + h * 64 + kt * 32 + 8 * g;
    f16x8 v = *(const f16x8*)p;
#pragma unroll
    for (int j = 0; j < 8; j++) v[j] = v[j] * (f16)0.18033688f;
    qf[kt].h = v;
  }

  float mR = -3.0e38f, lR = 0.0f;     // per-lane (one q row)
  f32x4 o2[4] = {};                   // o2[ntd][r] = O[d = ntd*16+g*4+r][q]

#define STAGE_KV(kv0_, buf_)                                                     \
  {                                                                              \
    _Pragma("unroll") for (int i = 0; i < 2; i++) {                              \
      int C = i * 256 + w * 64 + lane;                                           \
      int row = C >> 3;                                                          \
      int cbg = ((C & 7) ^ (row & 7)) * 8;                                       \
      gload16(qkv + (size_t)(b * S_LEN + (kv0_) + row) * 3072 + 1024 + h * 64 + cbg, \
              &Ks[buf_][(i * 256 + w * 64) * 8]);                                \
      gload16(vt + (size_t)(bh * 64 + row) * S_LEN + (kv0_) + cbg,               \
              &Vs[buf_][(i * 256 + w * 64) * 8]);                                \
    }                                                                            \
  }

  int cur = 0;
  STAGE_KV(0, 0);

  for (int kv0 = 0; kv0 < S_LEN; kv0 += 64) {
    __syncthreads();  // buf[cur] staged; prev reads done
    if (kv0 + 64 < S_LEN) STAGE_KV(kv0 + 64, cur ^ 1);  // overlaps compute

    // ---- QK^T (swapped): s[nt] rows = kv, cols = q
    f32x4 s[4] = {};
#pragma unroll
    for (int nt = 0; nt < 4; nt++) {
      const int row = nt * 16 + rA;
#pragma unroll
      for (int kt = 0; kt < 2; kt++) {
        Frag kf;
        kf.h = *(const f16x8*)(&Ks[cur][row * 64 + ((kt * 4 + g) ^ (row & 7)) * 8]);
        s[nt] = mfma16(kf.h, qf[kt].h, s[nt]);
      }
    }

    // ---- softmax: lane-local row (q = rA); reduce 16 regs + shfl 16/32
    float mx = fmaxf(fmaxf(fmaxf(s[0][0], s[0][1]), fmaxf(s[0][2], s[0][3])),
                     fmaxf(fmaxf(s[1][0], s[1][1]), fmaxf(s[1][2], s[1][3])));
    float mx2 = fmaxf(fmaxf(fmaxf(s[2][0], s[2][1]), fmaxf(s[2][2], s[2][3])),
                      fmaxf(fmaxf(s[3][0], s[3][1]), fmaxf(s[3][2], s[3][3])));
    mx = fmaxf(mx, mx2);
    mx = fmaxf(mx, __shfl_xor(mx, 16));
    mx = fmaxf(mx, __shfl_xor(mx, 32));

    bool ok = (mx - mR <= 8.0f);      // defer-max (T13)
    if (!__all(ok)) {
      float mn = fmaxf(mR, mx);
      float alpha = exp2f(mR - mn);
      mR = mn;
      lR *= alpha;
#pragma unroll
      for (int ntd = 0; ntd < 4; ntd++)
#pragma unroll
        for (int r = 0; r < 4; r++) o2[ntd][r] *= alpha;
    }

    float rs = 0.0f;
#pragma unroll
    for (int nt = 0; nt < 4; nt++)
#pragma unroll
      for (int r = 0; r < 4; r++) {
        float e0 = exp2f(s[nt][r] - mR);
        s[nt][r] = e0;
        rs += e0;
      }
    rs += __shfl_xor(rs, 16);
    rs += __shfl_xor(rs, 32);
    lR += rs;

    // ---- P -> f16 in-lane: ph[j] = {s[2j].r0..3, s[2j+1].r0..3}
    Frag ph[2];
#pragma unroll
    for (int j = 0; j < 2; j++)
#pragma unroll
      for (int r = 0; r < 4; r++) {
        ph[j].e[r] = (f16)s[2 * j][r];
        ph[j].e[4 + r] = (f16)s[2 * j + 1][r];
      }

    // ---- PV: o2[ntd] += V(rows d) x P  (A = Vs, B = ph; slot-consistent)
#pragma unroll
    for (int ntd = 0; ntd < 4; ntd++) {
      const int row = ntd * 16 + rA;
#pragma unroll
      for (int j = 0; j < 2; j++) {
        Frag vf;
        vf.h = *(const f16x8*)(&Vs[cur][row * 64 + ((j * 4 + g) ^ (row & 7)) * 8]);
        o2[ntd] = mfma16(vf.h, ph[j].h, o2[ntd]);
      }
    }

    cur ^= 1;
  }

  // ---- normalize + store: lane holds O[d = ntd*16+g*4+r][q = qrow]
  const float inv = 1.0f / lR;
#pragma unroll
  for (int ntd = 0; ntd < 4; ntd++) {
    union { f16 h[4]; u64 q; } pk;
#pragma unroll
    for (int r = 0; r < 4; r++) pk.h[r] = (f16)(o2[ntd][r] * inv);
    *(u64*)(attn_out + (size_t)(b * S_LEN + qrow) * DMODEL + h * 64 + ntd * 16 + g * 4) = pk.q;
  }
#undef STAGE_KV
}

// ---------------------------------------------------------------------------
extern "C" void kernel_launch(void* const* d_in, const int* in_sizes, int n_in,
                              void* d_out, int out_size, void* d_ws, size_t ws_size,
                              hipStream_t stream) {
  const float* x     = (const float*)d_in[0];
  const float* Wq    = (const float*)d_in[1];
  const float* bq    = (const float*)d_in[2];
  const float* Wk    = (const float*)d_in[3];
  const float* bk    = (const float*)d_in[4];
  const float* Wv    = (const float*)d_in[5];
  const float* bv    = (const float*)d_in[6];
  const float* Wo    = (const float*)d_in[7];
  const float* bo    = (const float*)d_in[8];
  const float* W1    = (const float*)d_in[9];
  const float* b1    = (const float*)d_in[10];
  const float* W2    = (const float*)d_in[11];
  const float* b2    = (const float*)d_in[12];
  const float* ln1g  = (const float*)d_in[13];
  const float* ln1b  = (const float*)d_in[14];
  const float* ln2g  = (const float*)d_in[15];
  const float* ln2b  = (const float*)d_in[16];
  float* out = (float*)d_out;
  char* ws = (char*)d_ws;

  size_t off = 0;
  f16* wqkv_t = (f16*)(ws + off); off += (size_t)3072 * 1024 * 2;   // 6 MB
  f16* wo_t   = (f16*)(ws + off); off += (size_t)1024 * 1024 * 2;   // 2 MB
  f16* w1_t   = (f16*)(ws + off); off += (size_t)4096 * 1024 * 2;   // 8 MB
  f16* w2_t   = (f16*)(ws + off); off += (size_t)1024 * 4096 * 2;   // 8 MB
  float* bqkv = (float*)(ws + off); off += 3072 * 4;                // 12 KB
  f16* regB   = (f16*)(ws + off); off += (size_t)MROWS * 1024 * 2;  // 8 MB (xln/attn_out/xln2)
  f16* qkv    = (f16*)(ws + off); off += (size_t)MROWS * 3072 * 2;  // 24 MB
  f16* vt     = (f16*)(ws + off); off += (size_t)MROWS * 1024 * 2;  // 8 MB
  f16* hbuf   = qkv;  // overlay: qkv+vt (32MB) dead after attention; FFN h = 32MB

  // 1. weights -> f16 transposed
  wtrans_kernel<<<dim3(32, 32), 256, 0, stream>>>(Wq, wqkv_t, 1024, 1024);
  wtrans_kernel<<<dim3(32, 32), 256, 0, stream>>>(Wk, wqkv_t + (size_t)1024 * 1024, 1024, 1024);
  wtrans_kernel<<<dim3(32, 32), 256, 0, stream>>>(Wv, wqkv_t + (size_t)2048 * 1024, 1024, 1024);
  wtrans_kernel<<<dim3(32, 32), 256, 0, stream>>>(Wo, wo_t, 1024, 1024);
  wtrans_kernel<<<dim3(128, 32), 256, 0, stream>>>(W1, w1_t, 1024, 4096);
  wtrans_kernel<<<dim3(32, 128), 256, 0, stream>>>(W2, w2_t, 4096, 1024);
  bias_concat_kernel<<<12, 256, 0, stream>>>(bq, bk, bv, bqkv);

  // 2. LN1(x) -> regB (f16)
  ln_kernel<<<MROWS, 256, 0, stream>>>(x, ln1g, ln1b, regB);

  // 3. fused QKV projection: [4096,1024] @ [1024,3072]
  gemm2<128, 128><<<dim3(24, 32), 256, 0, stream>>>(regB, 1024, wqkv_t, 1024, bqkv,
                                                    nullptr, nullptr, qkv, 3072,
                                                    3072, 1024, 0);
  // 4. V -> [bh*64+dk][s] with per-64-chunk k-slot permutation
  vtrans_kernel<<<dim3(32, 32), 256, 0, stream>>>(qkv, vt);

  // 5. attention -> regB (f16), 4 waves x 16 q-rows, 1024 blocks
  attn_kernel<<<dim3(32, 32), 256, 0, stream>>>(qkv, vt, regB);

  // 6. O projection + residual x -> d_out (fp32); 128x64 tiles -> 512 blocks
  gemm2<128, 64><<<dim3(16, 32), 256, 0, stream>>>(regB, 1024, wo_t, 1024, bo,
                                                   x, out, nullptr, 0,
                                                   1024, 1024, 0);
  // 7. LN2(d_out) -> regB
  ln_kernel<<<MROWS, 256, 0, stream>>>(out, ln2g, ln2b, regB);

  // 8. FFN1 + ReLU: [4096,1024]@[1024,4096] -> hbuf (f16)
  gemm2<128, 128><<<dim3(32, 32), 256, 0, stream>>>(regB, 1024, w1_t, 1024, b1,
                                                    nullptr, nullptr, hbuf, 4096,
                                                    4096, 1024, 1);
  // 9. FFN2 + residual: [4096,4096]@[4096,1024] + d_out -> d_out; 512 blocks
  gemm2<128, 64><<<dim3(16, 32), 256, 0, stream>>>(hbuf, 4096, w2_t, 4096, b2,
                                                   out, out, nullptr, 0,
                                                   1024, 4096, 0);
}

// Round 7
// 295.226 us; speedup vs baseline: 1.1855x; 1.0107x over previous
//
#include <hip/hip_runtime.h>

// Decoder layer: x + attn(LN1(x)); then + FFN(LN2(.))
// B=2, S=2048, D=1024, H=16, DK=64, FF=4096. fp32 in/out; f16 MFMA inside.

#define S_LEN 2048
#define DMODEL 1024
#define NHEADS 16
#define FFDIM 4096
#define MROWS 4096   // B*S

typedef _Float16 f16;
typedef _Float16 f16x8 __attribute__((ext_vector_type(8)));
typedef float f32x4 __attribute__((ext_vector_type(4)));
typedef unsigned long long u64;
typedef unsigned long long u64x2 __attribute__((ext_vector_type(2)));

union Frag { f16x8 h; u64 q[2]; f16 e[8]; };

__device__ __forceinline__ f32x4 mfma16(f16x8 a, f16x8 b, f32x4 c) {
  return __builtin_amdgcn_mfma_f32_16x16x32_f16(a, b, c, 0, 0, 0);
}

typedef __attribute__((address_space(1))) const void gvoid;
typedef __attribute__((address_space(3))) void lvoid;

__device__ __forceinline__ void gload16(const f16* gp, f16* lp) {
  __builtin_amdgcn_global_load_lds((gvoid*)gp, (lvoid*)lp, 16, 0, 0);
}

// ---------------- weight transpose+convert: W[K][N] fp32 -> Wt[N][K] f16 ----
__global__ __launch_bounds__(256) void wtrans_kernel(const float* __restrict__ W,
                                                     f16* __restrict__ Wt,
                                                     int K, int N) {
  __shared__ f16 tile[32][33];
  const int n0 = blockIdx.x * 32, k0 = blockIdx.y * 32;
  const int tx = threadIdx.x & 31, ty = threadIdx.x >> 5;  // 32 x 8
  for (int i = 0; i < 4; i++) {
    int k = ty + i * 8;
    tile[k][tx] = (f16)W[(size_t)(k0 + k) * N + n0 + tx];
  }
  __syncthreads();
  for (int i = 0; i < 4; i++) {
    int n = ty + i * 8;
    Wt[(size_t)(n0 + n) * K + k0 + tx] = tile[tx][n];
  }
}

__global__ void bias_concat_kernel(const float* __restrict__ bq,
                                   const float* __restrict__ bk,
                                   const float* __restrict__ bv,
                                   float* __restrict__ out) {
  int i = blockIdx.x * 256 + threadIdx.x;  // 3072 total
  float v = (i < 1024) ? bq[i] : (i < 2048) ? bk[i - 1024] : bv[i - 2048];
  out[i] = v;
}

// ---------------- LayerNorm fp32 -> f16 ------------------------------------
__global__ __launch_bounds__(256) void ln_kernel(const float* __restrict__ x,
                                                 const float* __restrict__ gw,
                                                 const float* __restrict__ bw,
                                                 f16* __restrict__ out) {
  const int row = blockIdx.x, t = threadIdx.x;
  const float* xr = x + (size_t)row * DMODEL;
  float4 v = *(const float4*)(xr + t * 4);
  float s = v.x + v.y + v.z + v.w;
  float s2 = v.x * v.x + v.y * v.y + v.z * v.z + v.w * v.w;
  for (int off = 1; off < 64; off <<= 1) {
    s += __shfl_xor(s, off);
    s2 += __shfl_xor(s2, off);
  }
  __shared__ float red[8];
  const int w = t >> 6, lane = t & 63;
  if (lane == 0) { red[w] = s; red[w + 4] = s2; }
  __syncthreads();
  s = red[0] + red[1] + red[2] + red[3];
  s2 = red[4] + red[5] + red[6] + red[7];
  float mu = s * (1.0f / DMODEL);
  float var = s2 * (1.0f / DMODEL) - mu * mu;
  float rstd = rsqrtf(var + 1e-6f);
  float4 g4 = *(const float4*)(gw + t * 4);
  float4 b4 = *(const float4*)(bw + t * 4);
  union { f16 h[4]; u64 q; } o;
  o.h[0] = (f16)((v.x - mu) * rstd * g4.x + b4.x);
  o.h[1] = (f16)((v.y - mu) * rstd * g4.y + b4.y);
  o.h[2] = (f16)((v.z - mu) * rstd * g4.z + b4.z);
  o.h[3] = (f16)((v.w - mu) * rstd * g4.w + b4.w);
  *(u64*)(out + (size_t)row * DMODEL + t * 4) = o.q;
}

// ---------------- GEMM: C = A[M][K] @ Bt[N][K]^T + bias ---------------------
// Counted-vmcnt schedule (T4): stageA issued 2 tiles ahead, stageB 1 tile
// ahead; raw s_barrier + asm vmcnt(4) so next tile's A-loads stay in flight
// across the wait (never drain to 0 in the main loop). lgkmcnt(0) +
// sched_barrier(0) before the barrier releasing buffer overwrites (rule #18).
// Both-sides XOR swizzle (rule #21). Consistent A/B K-mapping => exact.
template <int BM, int BN>
__global__ __launch_bounds__(256, 2) void gemm2(const f16* __restrict__ A, int lda,
                                                const f16* __restrict__ Bt, int ldb,
                                                const float* __restrict__ bias,
                                                const float* __restrict__ res,
                                                float* __restrict__ outf,
                                                f16* __restrict__ outh, int ldo,
                                                int N, int K, int relu) {
  constexpr int MT = BM / 32, NT = BN / 32;
  __shared__ f16 As[2][BM * 64];
  __shared__ f16 Bs[2][BN * 64];
  const int m0 = blockIdx.y * BM, n0 = blockIdx.x * BN;
  const int t = threadIdx.x;
  const int lane = t & 63, w = t >> 6;
  const int wr = w >> 1, wc = w & 1;
  const int rA = lane & 15, g = lane >> 4;

  f32x4 acc[MT][NT] = {};

  auto stageA = [&](int k0, int buf) {
#pragma unroll
    for (int p = 0; p < BM / 32; p++) {
      const int chunk = p * 256 + w * 64 + lane;
      const int row = chunk >> 3;
      const int cbg = ((chunk & 7) ^ (row & 7)) * 8;  // pre-swizzled source col
      gload16(A + (size_t)(m0 + row) * lda + k0 + cbg,
              &As[buf][(p * 256 + w * 64) * 8]);
    }
  };
  auto stageB = [&](int k0, int buf) {
#pragma unroll
    for (int p = 0; p < BN / 32; p++) {
      const int chunk = p * 256 + w * 64 + lane;
      const int row = chunk >> 3;
      const int cbg = ((chunk & 7) ^ (row & 7)) * 8;
      gload16(Bt + (size_t)(n0 + row) * ldb + k0 + cbg,
              &Bs[buf][(p * 256 + w * 64) * 8]);
    }
  };

  auto compute = [&](int cur) {
#pragma unroll
    for (int ks = 0; ks < 2; ks++) {
      Frag a[MT], b[NT];
#pragma unroll
      for (int mt = 0; mt < MT; mt++) {
        const int row = wr * (BM / 2) + mt * 16 + rA;
        a[mt].h = *(const f16x8*)(&As[cur][row * 64 + ((ks * 4 + g) ^ (row & 7)) * 8]);
      }
#pragma unroll
      for (int nt = 0; nt < NT; nt++) {
        const int row = wc * (BN / 2) + nt * 16 + rA;
        b[nt].h = *(const f16x8*)(&Bs[cur][row * 64 + ((ks * 4 + g) ^ (row & 7)) * 8]);
      }
#pragma unroll
      for (int mt = 0; mt < MT; mt++)
#pragma unroll
        for (int nt = 0; nt < NT; nt++)
          acc[mt][nt] = mfma16(a[mt].h, b[nt].h, acc[mt][nt]);
    }
  };

  const int nsteps = K / 64;  // >= 16 for all our shapes
  stageA(0, 0);
  stageB(0, 0);
  stageA(64, 1);

  for (int ts = 0; ts < nsteps - 1; ++ts) {
    const int cur = ts & 1;
    // Wait for tile ts (oldest loads); tile ts+1's A-loads (4) stay in flight.
    asm volatile("s_waitcnt vmcnt(4)" ::: "memory");
    __builtin_amdgcn_sched_barrier(0);
    __builtin_amdgcn_s_barrier();     // all waves: tile ts resident
    stageB(ts * 64 + 64, cur ^ 1);    // B of tile ts+1 (overlaps compute)
    compute(cur);
    asm volatile("s_waitcnt lgkmcnt(0)" ::: "memory");  // our LDS reads done
    __builtin_amdgcn_sched_barrier(0);
    __builtin_amdgcn_s_barrier();     // all waves done reading buf[cur]
    if (ts + 2 < nsteps) stageA(ts * 64 + 128, cur);  // A of tile ts+2
  }
  // final tile: nothing younger in flight -> full drain
  asm volatile("s_waitcnt vmcnt(0)" ::: "memory");
  __builtin_amdgcn_sched_barrier(0);
  __builtin_amdgcn_s_barrier();
  compute((nsteps - 1) & 1);

#pragma unroll
  for (int mt = 0; mt < MT; mt++) {
#pragma unroll
    for (int nt = 0; nt < NT; nt++) {
      const int col = n0 + wc * (BN / 2) + nt * 16 + rA;
      const int rowb = m0 + wr * (BM / 2) + mt * 16 + g * 4;
      const float bs = bias[col];
#pragma unroll
      for (int r = 0; r < 4; r++) {
        float v = acc[mt][nt][r] + bs;
        if (relu) v = fmaxf(v, 0.0f);
        if (res) v += res[(size_t)(rowb + r) * N + col];
        if (outf) outf[(size_t)(rowb + r) * N + col] = v;
        if (outh) outh[(size_t)(rowb + r) * ldo + col] = (f16)v;
      }
    }
  }
}

// ---------------- V transpose: qkv v-cols -> vt[bh*64+dk][s], k-slot perm ---
// Within each 64-aligned S-chunk, position pos holds kv index
// kv(pos) = (pos&32) | ((pos&4)<<2) | ((pos&0x18)>>1) | (pos&3)
// so a 16B read at pos = j*32+8g gives kv {j*32+4g+i, j*32+16+4g+i} — the
// PV A-fragment content matching the QK^T C-row -> PV B-slot alignment.
__global__ __launch_bounds__(256) void vtrans_kernel(const f16* __restrict__ qkv,
                                                     f16* __restrict__ vt) {
  const int bh = blockIdx.y;                 // 0..31
  const int s0 = blockIdx.x * 64;
  const int b = bh >> 4, h = bh & 15;
  __shared__ f16 tile[64][72];               // [s][dk]
  const int t = threadIdx.x;
  for (int pass = 0; pass < 2; pass++) {
    int sl = (t >> 3) + pass * 32;
    int dk0 = (t & 7) * 8;
    u64x2 v = *(const u64x2*)(qkv + (size_t)(b * S_LEN + s0 + sl) * 3072 + 2048 + h * 64 + dk0);
    *(u64x2*)(&tile[sl][dk0]) = v;
  }
  __syncthreads();
  for (int pass = 0; pass < 2; pass++) {
    int dk = (t >> 3) + pass * 32;
    int sc = (t & 7) * 8;
    union { u64x2 q; f16 u[8]; } o;
    for (int j = 0; j < 8; j++) {
      int pos = sc + j;
      int kv = (pos & 32) | ((pos & 4) << 2) | ((pos & 0x18) >> 1) | (pos & 3);
      o.u[j] = tile[kv][dk];
    }
    *(u64x2*)(vt + (size_t)(bh * 64 + dk) * S_LEN + s0 + sc) = o.q;
  }
}

// ---------------- flash attention: swapped QK^T, zero-shuffle PV ------------
// 4 waves x 16 q-rows (q = qw0 + rA, one q per lane). s = mfma(K, Q):
// C layout (m89): col = q = rA, row = kv = nt*16 + g*4 + reg. Softmax is
// lane-local (15 in-lane ops + 2 shfls). exp2'd scores convert f16 in-lane
// and feed PV's B-operand directly (C-row <-> B-k-slot alignment; V's
// A-fragment uses the same slot convention via the permuted vt).
__global__ __launch_bounds__(256, 4) void attn_kernel(const f16* __restrict__ qkv,
                                                      const f16* __restrict__ vt,
                                                      f16* __restrict__ attn_out) {
  const int qt0 = blockIdx.x * 64;    // q-tile base (64 rows/block)
  const int bh = blockIdx.y;          // 0..31
  const int b = bh >> 4, h = bh & 15;
  const int t = threadIdx.x;
  const int lane = t & 63, w = t >> 6;
  const int rA = lane & 15, g = lane >> 4;

  __shared__ f16 Ks[2][64 * 64];      // [kv 64][dk 64], swizzled 16B blocks
  __shared__ f16 Vs[2][64 * 64];      // [dk 64][kv-perm 64], swizzled blocks

  // Q fragment (B-operand): col q = qt0 + w*16 + rA; pre-scale 0.125*log2e
  const int qrow = qt0 + w * 16 + rA;
  Frag qf[2];
#pragma unroll
  for (int kt = 0; kt < 2; kt++) {
    const f16* p = qkv + (size_t)(b * S_LEN + qrow) * 3072 + h * 64 + kt * 32 + 8 * g;
    f16x8 v = *(const f16x8*)p;
#pragma unroll
    for (int j = 0; j < 8; j++) v[j] = v[j] * (f16)0.18033688f;
    qf[kt].h = v;
  }

  float mR = -3.0e38f, lR = 0.0f;     // per-lane (one q row)
  f32x4 o2[4] = {};                   // o2[ntd][r] = O[d = ntd*16+g*4+r][q]

#define STAGE_KV(kv0_, buf_)                                                     \
  {                                                                              \
    _Pragma("unroll") for (int i = 0; i < 2; i++) {                              \
      int C = i * 256 + w * 64 + lane;                                           \
      int row = C >> 3;                                                          \
      int cbg = ((C & 7) ^ (row & 7)) * 8;                                       \
      gload16(qkv + (size_t)(b * S_LEN + (kv0_) + row) * 3072 + 1024 + h * 64 + cbg, \
              &Ks[buf_][(i * 256 + w * 64) * 8]);                                \
      gload16(vt + (size_t)(bh * 64 + row) * S_LEN + (kv0_) + cbg,               \
              &Vs[buf_][(i * 256 + w * 64) * 8]);                                \
    }                                                                            \
  }

  int cur = 0;
  STAGE_KV(0, 0);

  for (int kv0 = 0; kv0 < S_LEN; kv0 += 64) {
    __syncthreads();  // buf[cur] staged; prev reads done
    if (kv0 + 64 < S_LEN) STAGE_KV(kv0 + 64, cur ^ 1);  // overlaps compute

    // ---- QK^T (swapped): s[nt] rows = kv, cols = q
    f32x4 s[4] = {};
#pragma unroll
    for (int nt = 0; nt < 4; nt++) {
      const int row = nt * 16 + rA;
#pragma unroll
      for (int kt = 0; kt < 2; kt++) {
        Frag kf;
        kf.h = *(const f16x8*)(&Ks[cur][row * 64 + ((kt * 4 + g) ^ (row & 7)) * 8]);
        s[nt] = mfma16(kf.h, qf[kt].h, s[nt]);
      }
    }

    // ---- softmax: lane-local row (q = rA); reduce 16 regs + shfl 16/32
    float mx = fmaxf(fmaxf(fmaxf(s[0][0], s[0][1]), fmaxf(s[0][2], s[0][3])),
                     fmaxf(fmaxf(s[1][0], s[1][1]), fmaxf(s[1][2], s[1][3])));
    float mx2 = fmaxf(fmaxf(fmaxf(s[2][0], s[2][1]), fmaxf(s[2][2], s[2][3])),
                      fmaxf(fmaxf(s[3][0], s[3][1]), fmaxf(s[3][2], s[3][3])));
    mx = fmaxf(mx, mx2);
    mx = fmaxf(mx, __shfl_xor(mx, 16));
    mx = fmaxf(mx, __shfl_xor(mx, 32));

    bool ok = (mx - mR <= 8.0f);      // defer-max (T13)
    if (!__all(ok)) {
      float mn = fmaxf(mR, mx);
      float alpha = exp2f(mR - mn);
      mR = mn;
      lR *= alpha;
#pragma unroll
      for (int ntd = 0; ntd < 4; ntd++)
#pragma unroll
        for (int r = 0; r < 4; r++) o2[ntd][r] *= alpha;
    }

    float rs = 0.0f;
#pragma unroll
    for (int nt = 0; nt < 4; nt++)
#pragma unroll
      for (int r = 0; r < 4; r++) {
        float e0 = exp2f(s[nt][r] - mR);
        s[nt][r] = e0;
        rs += e0;
      }
    rs += __shfl_xor(rs, 16);
    rs += __shfl_xor(rs, 32);
    lR += rs;

    // ---- P -> f16 in-lane: ph[j] = {s[2j].r0..3, s[2j+1].r0..3}
    Frag ph[2];
#pragma unroll
    for (int j = 0; j < 2; j++)
#pragma unroll
      for (int r = 0; r < 4; r++) {
        ph[j].e[r] = (f16)s[2 * j][r];
        ph[j].e[4 + r] = (f16)s[2 * j + 1][r];
      }

    // ---- PV: o2[ntd] += V(rows d) x P  (A = Vs, B = ph; slot-consistent)
#pragma unroll
    for (int ntd = 0; ntd < 4; ntd++) {
      const int row = ntd * 16 + rA;
#pragma unroll
      for (int j = 0; j < 2; j++) {
        Frag vf;
        vf.h = *(const f16x8*)(&Vs[cur][row * 64 + ((j * 4 + g) ^ (row & 7)) * 8]);
        o2[ntd] = mfma16(vf.h, ph[j].h, o2[ntd]);
      }
    }

    cur ^= 1;
  }

  // ---- normalize + store: lane holds O[d = ntd*16+g*4+r][q = qrow]
  const float inv = 1.0f / lR;
#pragma unroll
  for (int ntd = 0; ntd < 4; ntd++) {
    union { f16 h[4]; u64 q; } pk;
#pragma unroll
    for (int r = 0; r < 4; r++) pk.h[r] = (f16)(o2[ntd][r] * inv);
    *(u64*)(attn_out + (size_t)(b * S_LEN + qrow) * DMODEL + h * 64 + ntd * 16 + g * 4) = pk.q;
  }
#undef STAGE_KV
}

// ---------------------------------------------------------------------------
extern "C" void kernel_launch(void* const* d_in, const int* in_sizes, int n_in,
                              void* d_out, int out_size, void* d_ws, size_t ws_size,
                              hipStream_t stream) {
  const float* x     = (const float*)d_in[0];
  const float* Wq    = (const float*)d_in[1];
  const float* bq    = (const float*)d_in[2];
  const float* Wk    = (const float*)d_in[3];
  const float* bk    = (const float*)d_in[4];
  const float* Wv    = (const float*)d_in[5];
  const float* bv    = (const float*)d_in[6];
  const float* Wo    = (const float*)d_in[7];
  const float* bo    = (const float*)d_in[8];
  const float* W1    = (const float*)d_in[9];
  const float* b1    = (const float*)d_in[10];
  const float* W2    = (const float*)d_in[11];
  const float* b2    = (const float*)d_in[12];
  const float* ln1g  = (const float*)d_in[13];
  const float* ln1b  = (const float*)d_in[14];
  const float* ln2g  = (const float*)d_in[15];
  const float* ln2b  = (const float*)d_in[16];
  float* out = (float*)d_out;
  char* ws = (char*)d_ws;

  size_t off = 0;
  f16* wqkv_t = (f16*)(ws + off); off += (size_t)3072 * 1024 * 2;   // 6 MB
  f16* wo_t   = (f16*)(ws + off); off += (size_t)1024 * 1024 * 2;   // 2 MB
  f16* w1_t   = (f16*)(ws + off); off += (size_t)4096 * 1024 * 2;   // 8 MB
  f16* w2_t   = (f16*)(ws + off); off += (size_t)1024 * 4096 * 2;   // 8 MB
  float* bqkv = (float*)(ws + off); off += 3072 * 4;                // 12 KB
  f16* regB   = (f16*)(ws + off); off += (size_t)MROWS * 1024 * 2;  // 8 MB (xln/attn_out/xln2)
  f16* qkv    = (f16*)(ws + off); off += (size_t)MROWS * 3072 * 2;  // 24 MB
  f16* vt     = (f16*)(ws + off); off += (size_t)MROWS * 1024 * 2;  // 8 MB
  f16* hbuf   = qkv;  // overlay: qkv+vt (32MB) dead after attention; FFN h = 32MB

  // 1. weights -> f16 transposed
  wtrans_kernel<<<dim3(32, 32), 256, 0, stream>>>(Wq, wqkv_t, 1024, 1024);
  wtrans_kernel<<<dim3(32, 32), 256, 0, stream>>>(Wk, wqkv_t + (size_t)1024 * 1024, 1024, 1024);
  wtrans_kernel<<<dim3(32, 32), 256, 0, stream>>>(Wv, wqkv_t + (size_t)2048 * 1024, 1024, 1024);
  wtrans_kernel<<<dim3(32, 32), 256, 0, stream>>>(Wo, wo_t, 1024, 1024);
  wtrans_kernel<<<dim3(128, 32), 256, 0, stream>>>(W1, w1_t, 1024, 4096);
  wtrans_kernel<<<dim3(32, 128), 256, 0, stream>>>(W2, w2_t, 4096, 1024);
  bias_concat_kernel<<<12, 256, 0, stream>>>(bq, bk, bv, bqkv);

  // 2. LN1(x) -> regB (f16)
  ln_kernel<<<MROWS, 256, 0, stream>>>(x, ln1g, ln1b, regB);

  // 3. fused QKV projection: [4096,1024] @ [1024,3072]
  gemm2<128, 128><<<dim3(24, 32), 256, 0, stream>>>(regB, 1024, wqkv_t, 1024, bqkv,
                                                    nullptr, nullptr, qkv, 3072,
                                                    3072, 1024, 0);
  // 4. V -> [bh*64+dk][s] with per-64-chunk k-slot permutation
  vtrans_kernel<<<dim3(32, 32), 256, 0, stream>>>(qkv, vt);

  // 5. attention -> regB (f16), 4 waves x 16 q-rows, 1024 blocks
  attn_kernel<<<dim3(32, 32), 256, 0, stream>>>(qkv, vt, regB);

  // 6. O projection + residual x -> d_out (fp32); 128x64 tiles -> 512 blocks
  gemm2<128, 64><<<dim3(16, 32), 256, 0, stream>>>(regB, 1024, wo_t, 1024, bo,
                                                   x, out, nullptr, 0,
                                                   1024, 1024, 0);
  // 7. LN2(d_out) -> regB
  ln_kernel<<<MROWS, 256, 0, stream>>>(out, ln2g, ln2b, regB);

  // 8. FFN1 + ReLU: [4096,1024]@[1024,4096] -> hbuf (f16)
  gemm2<128, 128><<<dim3(32, 32), 256, 0, stream>>>(regB, 1024, w1_t, 1024, b1,
                                                    nullptr, nullptr, hbuf, 4096,
                                                    4096, 1024, 1);
  // 9. FFN2 + residual: [4096,4096]@[4096,1024] + d_out -> d_out; 512 blocks
  gemm2<128, 64><<<dim3(16, 32), 256, 0, stream>>>(hbuf, 4096, w2_t, 4096, b2,
                                                   out, out, nullptr, 0,
                                                   1024, 4096, 0);
}